// Round 4
// baseline (28.479 us; speedup 1.0000x reference)
//
#include <hip/hip_runtime.h>

// GATconv_72464688218548 — outputs are (adj, log_softmax(elu(...), axis=1))
// where the second output has shape (4096, 1): log_softmax over a singleton
// axis is identically 0 for any finite input. So:
//   d_out[0 : N*N]      = adj   (67 MB pass-through)
//   d_out[N*N : N*N+N]  = 0
// Pure HBM-bound copy (134 MB round trip). 4 vec4/thread, loads-before-stores
// for MLP, non-temporal hints to bypass L2 pollution.
//
// NOTE: __builtin_nontemporal_* rejects HIP_vector_type (float4) pointers —
// use a clang native ext_vector_type instead (same 16B layout/alignment).

typedef float f4 __attribute__((ext_vector_type(4)));

#define NN_F4 (4096ull * 4096ull / 4ull)   // 4,194,304 vec4 elements
#define TAIL_F4 (4096ull / 4ull)           // 1,024 vec4 of zeros

__global__ __launch_bounds__(256) void gat_copy_kernel(
    const f4* __restrict__ adj, f4* __restrict__ out) {
    const size_t nthreads = (size_t)gridDim.x * blockDim.x;   // 1,048,576
    const size_t i = (size_t)blockIdx.x * blockDim.x + threadIdx.x;

    // Zero tail: out2 = zeros(4096) — log_softmax over singleton axis.
    if (i < TAIL_F4) {
        const f4 z = {0.f, 0.f, 0.f, 0.f};
        __builtin_nontemporal_store(z, &out[NN_F4 + i]);
    }

    // 4 vec4 per thread; issue all 4 loads before any store (MLP),
    // non-temporal both ways (streamed-once data, don't cache).
    const f4 a0 = __builtin_nontemporal_load(&adj[i]);
    const f4 a1 = __builtin_nontemporal_load(&adj[i + nthreads]);
    const f4 a2 = __builtin_nontemporal_load(&adj[i + 2 * nthreads]);
    const f4 a3 = __builtin_nontemporal_load(&adj[i + 3 * nthreads]);
    __builtin_nontemporal_store(a0, &out[i]);
    __builtin_nontemporal_store(a1, &out[i + nthreads]);
    __builtin_nontemporal_store(a2, &out[i + 2 * nthreads]);
    __builtin_nontemporal_store(a3, &out[i + 3 * nthreads]);
}

extern "C" void kernel_launch(void* const* d_in, const int* in_sizes, int n_in,
                              void* d_out, int out_size, void* d_ws, size_t ws_size,
                              hipStream_t stream) {
    const f4* adj = (const f4*)d_in[0];
    f4* out = (f4*)d_out;

    // 4096 blocks x 256 threads = 1,048,576 threads; 4 vec4/thread
    // covers NN_F4 = 4,194,304 exactly.
    gat_copy_kernel<<<4096, 256, 0, stream>>>(adj, out);
}

// Round 5
// 28.130 us; speedup vs baseline: 1.0124x; 1.0124x over previous
//
#include <hip/hip_runtime.h>

// GATconv_72464688218548 — outputs are (adj, log_softmax(elu(...), axis=1))
// where the second output has shape (4096, 1): log_softmax over a singleton
// axis is identically 0 for any finite input. So:
//   d_out[0 : N*N]      = adj   (67 MB pass-through)
//   d_out[N*N : N*N+N]  = 0
// Pure HBM-bound copy (134 MB round trip).
//
// R4 lesson: NT *stores* regressed −11% (bypass L2 write-combining; the
// harness's own fills hit 6.8 TB/s through cached writes). This version:
// NT loads only (adj is streamed-once; keep it out of L2 so the cache
// serves the write stream), regular stores, grid-stride like R2.

typedef float f4 __attribute__((ext_vector_type(4)));

#define NN_F4 (4096ull * 4096ull / 4ull)   // 4,194,304 vec4 elements
#define TAIL_F4 (4096ull / 4ull)           // 1,024 vec4 of zeros

__global__ __launch_bounds__(256) void gat_copy_kernel(
    const f4* __restrict__ adj, f4* __restrict__ out) {
    const size_t stride = (size_t)gridDim.x * blockDim.x;   // 2,097,152
    size_t i = (size_t)blockIdx.x * blockDim.x + threadIdx.x;

    // Zero tail: out2 = zeros(4096) — log_softmax over singleton axis.
    if (i < TAIL_F4) {
        const f4 z = {0.f, 0.f, 0.f, 0.f};
        out[NN_F4 + i] = z;
    }

    // Grid-stride: 2 vec4 per thread. NT load (stream-once read),
    // regular cached store (L2 write-combining).
    for (; i < NN_F4; i += stride) {
        out[i] = __builtin_nontemporal_load(&adj[i]);
    }
}

extern "C" void kernel_launch(void* const* d_in, const int* in_sizes, int n_in,
                              void* d_out, int out_size, void* d_ws, size_t ws_size,
                              hipStream_t stream) {
    const f4* adj = (const f4*)d_in[0];
    f4* out = (f4*)d_out;

    // 8192 blocks x 256 threads = 2,097,152 threads; 2 vec4/thread.
    gat_copy_kernel<<<8192, 256, 0, stream>>>(adj, out);
}

// Round 6
// 26.005 us; speedup vs baseline: 1.0951x; 1.0817x over previous
//
#include <hip/hip_runtime.h>

// GATconv_72464688218548 — outputs are (adj, log_softmax(elu(...), axis=1))
// where the second output has shape (4096, 1): log_softmax over a singleton
// axis is identically 0 for any finite input. So:
//   d_out[0 : N*N]      = adj   (67 MB pass-through)
//   d_out[N*N : N*N+N]  = 0
// Pure HBM-bound copy (134 MB round trip).
//
// History: R2 grid-stride cached = 25.7 µs (5.2 TB/s). R4 NT-stores = 28.5,
// R5 NT-loads = 28.1 — NT hints hurt on both sides; cached wins.
// This round: clean ILP test — R4's 4-loads-before-4-stores structure with
// PLAIN CACHED accesses (single-variable A/B vs both R2 and R4).

typedef float f4 __attribute__((ext_vector_type(4)));

#define NN_F4 (4096ull * 4096ull / 4ull)   // 4,194,304 vec4 elements
#define TAIL_F4 (4096ull / 4ull)           // 1,024 vec4 of zeros

__global__ __launch_bounds__(256) void gat_copy_kernel(
    const f4* __restrict__ adj, f4* __restrict__ out) {
    const size_t nthreads = (size_t)gridDim.x * blockDim.x;   // 1,048,576
    const size_t i = (size_t)blockIdx.x * blockDim.x + threadIdx.x;

    // Zero tail: out2 = zeros(4096) — log_softmax over singleton axis.
    if (i < TAIL_F4) {
        const f4 z = {0.f, 0.f, 0.f, 0.f};
        out[NN_F4 + i] = z;
    }

    // 4 vec4/thread; all 4 loads in flight before any store (ILP),
    // plain cached accesses (NT regressed in R4/R5).
    const f4 a0 = adj[i];
    const f4 a1 = adj[i + nthreads];
    const f4 a2 = adj[i + 2 * nthreads];
    const f4 a3 = adj[i + 3 * nthreads];
    out[i] = a0;
    out[i + nthreads] = a1;
    out[i + 2 * nthreads] = a2;
    out[i + 3 * nthreads] = a3;
}

extern "C" void kernel_launch(void* const* d_in, const int* in_sizes, int n_in,
                              void* d_out, int out_size, void* d_ws, size_t ws_size,
                              hipStream_t stream) {
    const f4* adj = (const f4*)d_in[0];
    f4* out = (f4*)d_out;

    // 4096 blocks x 256 threads = 1,048,576 threads; 4 vec4/thread
    // covers NN_F4 = 4,194,304 exactly.
    gat_copy_kernel<<<4096, 256, 0, stream>>>(adj, out);
}